// Round 1
// baseline (55.582 us; speedup 1.0000x reference)
//
#include <hip/hip_runtime.h>
#include <hip/hip_bf16.h>

#define BLOCK 256
#define GRID  2048

// Stable BCE-with-logits: log(1+exp(x)) - x*t = max(x,0) + log1p(exp(-|x|)) - x*t
__device__ __forceinline__ float bce_elem(float x, float t) {
    return fmaxf(x, 0.0f) + log1pf(__expf(-fabsf(x))) - x * t;
}

__global__ __launch_bounds__(BLOCK) void bce_partial_kernel(
        const float4* __restrict__ x4,
        const float4* __restrict__ t4,
        double* __restrict__ acc,
        int n4) {
    float sum = 0.0f;
    const int stride = gridDim.x * blockDim.x;
    for (int i = blockIdx.x * blockDim.x + threadIdx.x; i < n4; i += stride) {
        const float4 xv = x4[i];
        const float4 tv = t4[i];
        // One float4 covers two [B,2] rows: (x,y) = row 2i, (z,w) = row 2i+1.
        const float m0 = (tv.x + tv.y > 0.0f) ? 1.0f : 0.0f;
        const float m1 = (tv.z + tv.w > 0.0f) ? 1.0f : 0.0f;
        const float l0 = bce_elem(xv.x, tv.x) + bce_elem(xv.y, tv.y);
        const float l1 = bce_elem(xv.z, tv.z) + bce_elem(xv.w, tv.w);
        sum += m0 * l0 + m1 * l1;
    }

    // 64-lane wave reduction
    #pragma unroll
    for (int off = 32; off > 0; off >>= 1)
        sum += __shfl_down(sum, off, 64);

    __shared__ float wsum[BLOCK / 64];
    const int lane = threadIdx.x & 63;
    const int wid  = threadIdx.x >> 6;
    if (lane == 0) wsum[wid] = sum;
    __syncthreads();

    if (threadIdx.x == 0) {
        float b = 0.0f;
        #pragma unroll
        for (int w = 0; w < BLOCK / 64; ++w) b += wsum[w];
        atomicAdd(acc, (double)b);  // device-scope, one per block (2048 total)
    }
}

__global__ void bce_finalize_kernel(const double* __restrict__ acc,
                                    float* __restrict__ out,
                                    double inv_n) {
    out[0] = (float)(acc[0] * inv_n);
}

extern "C" void kernel_launch(void* const* d_in, const int* in_sizes, int n_in,
                              void* d_out, int out_size, void* d_ws, size_t ws_size,
                              hipStream_t stream) {
    const float* x = (const float*)d_in[0];   // inputs  [B,2] f32
    const float* t = (const float*)d_in[1];   // targets [B,2] f32
    float* out = (float*)d_out;
    double* acc = (double*)d_ws;

    const int n  = in_sizes[0];   // B*C = 16777216, divisible by 4
    const int n4 = n / 4;

    hipMemsetAsync(acc, 0, sizeof(double), stream);

    bce_partial_kernel<<<GRID, BLOCK, 0, stream>>>(
        (const float4*)x, (const float4*)t, acc, n4);

    bce_finalize_kernel<<<1, 1, 0, stream>>>(acc, out, 1.0 / (double)n);
}

// Round 3
// 51.008 us; speedup vs baseline: 1.0897x; 1.0897x over previous
//
#include <hip/hip_runtime.h>
#include <hip/hip_bf16.h>

#define BLOCK 256
#define GRID  2048

// Stable BCE-with-logits via native hardware transcendentals:
//   log(1+exp(x)) - x*t = max(x,0) + log(1 + exp(-|x|)) - x*t
// __expf/__logf lower to single v_exp_f32/v_log_f32 (+mul by log2e/ln2).
// |x| <= ~6 for N(0,1) inputs, so e = exp(-|x|) in (0.002, 1]; absolute
// error of log(1+e) in f32 ~1e-7 — far below the 1.2e-2 threshold.
__device__ __forceinline__ float bce_elem(float x, float t) {
    const float e  = __expf(-fabsf(x));
    const float sp = fmaxf(x, 0.0f) + __logf(1.0f + e);
    return __builtin_fmaf(-x, t, sp);
}

__global__ __launch_bounds__(BLOCK) void bce_partial_kernel(
        const float4* __restrict__ x4,
        const float4* __restrict__ t4,
        double* __restrict__ acc,
        int n4) {
    float sum = 0.0f;
    const int stride = gridDim.x * blockDim.x;
    for (int i = blockIdx.x * blockDim.x + threadIdx.x; i < n4; i += stride) {
        const float4 xv = x4[i];
        const float4 tv = t4[i];
        // One float4 covers two [B,2] rows: (x,y) = row 2i, (z,w) = row 2i+1.
        const float m0 = (tv.x + tv.y > 0.0f) ? 1.0f : 0.0f;
        const float m1 = (tv.z + tv.w > 0.0f) ? 1.0f : 0.0f;
        const float l0 = bce_elem(xv.x, tv.x) + bce_elem(xv.y, tv.y);
        const float l1 = bce_elem(xv.z, tv.z) + bce_elem(xv.w, tv.w);
        sum += m0 * l0 + m1 * l1;
    }

    // 64-lane wave reduction
    #pragma unroll
    for (int off = 32; off > 0; off >>= 1)
        sum += __shfl_down(sum, off, 64);

    __shared__ float wsum[BLOCK / 64];
    const int lane = threadIdx.x & 63;
    const int wid  = threadIdx.x >> 6;
    if (lane == 0) wsum[wid] = sum;
    __syncthreads();

    if (threadIdx.x == 0) {
        float b = 0.0f;
        #pragma unroll
        for (int w = 0; w < BLOCK / 64; ++w) b += wsum[w];
        atomicAdd(acc, (double)b);  // one per block (2048 total)
    }
}

__global__ void bce_finalize_kernel(const double* __restrict__ acc,
                                    float* __restrict__ out,
                                    double inv_n) {
    out[0] = (float)(acc[0] * inv_n);
}

extern "C" void kernel_launch(void* const* d_in, const int* in_sizes, int n_in,
                              void* d_out, int out_size, void* d_ws, size_t ws_size,
                              hipStream_t stream) {
    const float* x = (const float*)d_in[0];   // inputs  [B,2] f32
    const float* t = (const float*)d_in[1];   // targets [B,2] f32
    float* out = (float*)d_out;
    double* acc = (double*)d_ws;

    const int n  = in_sizes[0];   // B*C = 16777216, divisible by 4
    const int n4 = n / 4;

    (void)hipMemsetAsync(acc, 0, sizeof(double), stream);

    bce_partial_kernel<<<GRID, BLOCK, 0, stream>>>(
        (const float4*)x, (const float4*)t, acc, n4);

    bce_finalize_kernel<<<1, 1, 0, stream>>>(acc, out, 1.0 / (double)n);
}

// Round 4
// 28.063 us; speedup vs baseline: 1.9806x; 1.8176x over previous
//
#include <hip/hip_runtime.h>
#include <hip/hip_bf16.h>

#define BLOCK 256
#define GRID  2048   // == 8 blocks/CU x 256 CUs: whole grid co-resident

// Stable BCE-with-logits via native hardware transcendentals:
//   log(1+exp(x)) - x*t = max(x,0) + log(1 + exp(-|x|)) - x*t
__device__ __forceinline__ float bce_elem(float x, float t) {
    const float e  = __expf(-fabsf(x));
    const float sp = fmaxf(x, 0.0f) + __logf(1.0f + e);
    return __builtin_fmaf(-x, t, sp);
}

__global__ __launch_bounds__(BLOCK) void bce_partial_kernel(
        const float4* __restrict__ x4,
        const float4* __restrict__ t4,
        float* __restrict__ partials,   // [GRID] per-block sums, NO atomics
        int n4) {
    float sum = 0.0f;
    const int stride = gridDim.x * blockDim.x;
    for (int i = blockIdx.x * blockDim.x + threadIdx.x; i < n4; i += stride) {
        const float4 xv = x4[i];
        const float4 tv = t4[i];
        // One float4 covers two [B,2] rows: (x,y) = row 2i, (z,w) = row 2i+1.
        const float m0 = (tv.x + tv.y > 0.0f) ? 1.0f : 0.0f;
        const float m1 = (tv.z + tv.w > 0.0f) ? 1.0f : 0.0f;
        const float l0 = bce_elem(xv.x, tv.x) + bce_elem(xv.y, tv.y);
        const float l1 = bce_elem(xv.z, tv.z) + bce_elem(xv.w, tv.w);
        sum += m0 * l0 + m1 * l1;
    }

    // 64-lane wave reduction
    #pragma unroll
    for (int off = 32; off > 0; off >>= 1)
        sum += __shfl_down(sum, off, 64);

    __shared__ float wsum[BLOCK / 64];
    const int lane = threadIdx.x & 63;
    const int wid  = threadIdx.x >> 6;
    if (lane == 0) wsum[wid] = sum;
    __syncthreads();

    if (threadIdx.x == 0) {
        float b = 0.0f;
        #pragma unroll
        for (int w = 0; w < BLOCK / 64; ++w) b += wsum[w];
        partials[blockIdx.x] = b;       // plain store, one per block
    }
}

__global__ __launch_bounds__(BLOCK) void bce_finalize_kernel(
        const float* __restrict__ partials,
        float* __restrict__ out,
        double inv_n) {
    // 256 threads reduce GRID=2048 partials; double accumulation.
    double s = 0.0;
    #pragma unroll
    for (int k = 0; k < GRID / BLOCK; ++k)
        s += (double)partials[threadIdx.x + k * BLOCK];

    #pragma unroll
    for (int off = 32; off > 0; off >>= 1)
        s += __shfl_down(s, off, 64);

    __shared__ double wsum[BLOCK / 64];
    const int lane = threadIdx.x & 63;
    const int wid  = threadIdx.x >> 6;
    if (lane == 0) wsum[wid] = s;
    __syncthreads();

    if (threadIdx.x == 0) {
        double b = 0.0;
        #pragma unroll
        for (int w = 0; w < BLOCK / 64; ++w) b += wsum[w];
        out[0] = (float)(b * inv_n);
    }
}

extern "C" void kernel_launch(void* const* d_in, const int* in_sizes, int n_in,
                              void* d_out, int out_size, void* d_ws, size_t ws_size,
                              hipStream_t stream) {
    const float* x = (const float*)d_in[0];   // inputs  [B,2] f32
    const float* t = (const float*)d_in[1];   // targets [B,2] f32
    float* out = (float*)d_out;
    float* partials = (float*)d_ws;           // 2048 * 4 B = 8 KB scratch

    const int n  = in_sizes[0];   // B*C = 16777216, divisible by 4
    const int n4 = n / 4;

    bce_partial_kernel<<<GRID, BLOCK, 0, stream>>>(
        (const float4*)x, (const float4*)t, partials, n4);

    bce_finalize_kernel<<<1, BLOCK, 0, stream>>>(partials, out, 1.0 / (double)n);
}